// Round 4
// baseline (9094.654 us; speedup 1.0000x reference)
//
#include <hip/hip_runtime.h>
#include <stdint.h>

#define SLEN 4096
#define EDIM 256
#define HD 256
#define G4 1024   // 4*HD
#define KT 20
#define START_ID 18
#define STOP_ID 19

// K-split-4 weight layout for k_lstm: each thread owns ALL 4 gate-rows of one unit
// over a quarter of K (64 fp16). 128 weight dwords = 32 uint4 chunks:
// chunks 0-7 gate i, 8-15 gate f, 16-23 gate g, 24-31 gate o.
// Chunks 0..22 (92 dwords) in VGPRs; chunks 23..31 (9 uint4) in LDS tail.
#define NLC 9           // LDS tail chunks (uint4 per thread)
#define HPAD 144        // bytes per K-quarter stripe in h buffer (128 data + 16 pad)
#define HBUF (4 * HPAD) // 576 B per h buffer
#define LSTM_LDS_BYTES (2048 + 1024 * NLC * 16)   // h dbuf + tail weights = 149504

typedef _Float16 half_t;
typedef _Float16 half2_t __attribute__((ext_vector_type(2)));

__device__ __forceinline__ float dot2(uint32_t w, uint32_t h, float acc) {
#if __has_builtin(__builtin_amdgcn_fdot2)
    return __builtin_amdgcn_fdot2(__builtin_bit_cast(half2_t, w),
                                  __builtin_bit_cast(half2_t, h), acc, false);
#else
    half2_t wv = __builtin_bit_cast(half2_t, w);
    half2_t hv = __builtin_bit_cast(half2_t, h);
    acc += (float)wv.x * (float)hv.x;
    acc += (float)wv.y * (float)hv.y;
    return acc;
#endif
}

__device__ __forceinline__ float fsig(float x) { return 1.f / (1.f + __expf(-x)); }
__device__ __forceinline__ float ftanh(float x) { return 1.f - 2.f / (__expf(2.f * x) + 1.f); }

// k_lstm thread mapping (K-split-4):
//   w = t>>6, l = t&63, kq = l>>4 (K quarter), lj = l&15, unit j = 16w + lj
//   thread partial-dots rows {i,f,g,o}*256 + j over K in [kq*64, kq*64+64)
//   butterfly (xor16 then xor32) sums the 4 quarters -> every lane has full z quad.

// ---------------- prep: transpose w_ih into [d][e][o] ----------------
__global__ __launch_bounds__(256) void k_transpose_ih(const float* __restrict__ wf,
                                                      const float* __restrict__ wb,
                                                      float* __restrict__ wT) {
    __shared__ float tile[32][33];
    int d = blockIdx.z;
    const float* w = d ? wb : wf;
    int ob = blockIdx.x * 32;  // over 1024 rows
    int eb = blockIdx.y * 32;  // over 256 cols
    int tx = threadIdx.x & 31, ty = threadIdx.x >> 5;
#pragma unroll
    for (int r = 0; r < 32; r += 8)
        tile[ty + r][tx] = w[(long)(ob + ty + r) * EDIM + eb + tx];
    __syncthreads();
    float* dst = wT + (long)d * EDIM * G4;
#pragma unroll
    for (int r = 0; r < 32; r += 8)
        dst[(long)(eb + ty + r) * G4 + ob + tx] = tile[tx][ty + r];
}

// ---------------- prep: pack w_hh to fp16 in K-split-4 lstm thread order ----------------
__global__ __launch_bounds__(1024) void k_pack_hh(const float* __restrict__ whf,
                                                  const float* __restrict__ whb,
                                                  uint32_t* __restrict__ wpack,
                                                  uint32_t* __restrict__ wtail) {
    int d = blockIdx.y;
    const float* W = d ? whb : whf;
    int t = threadIdx.x;
    int l = t & 63;
    int w = t >> 6;
    int kq = l >> 4;
    int j = (w << 4) | (l & 15);
    int bx = blockIdx.x;  // 0..91 -> wpack dwords, 92..100 -> wtail chunks

    auto packdw = [&](int dd) -> uint32_t {
        int cc = dd >> 2, qq = dd & 3;          // chunk 0..31, dword-in-chunk
        int gate = cc >> 3;                      // chunks 0-7:i 8-15:f 16-23:g 24-31:o
        int row = gate * 256 + j;
        int k = kq * 64 + (cc & 7) * 8 + qq * 2;
        half2_t p = {(half_t)W[(long)row * HD + k], (half_t)W[(long)row * HD + k + 1]};
        return __builtin_bit_cast(uint32_t, p);
    };

    if (bx < 92) {
        wpack[(d * 92 + bx) * 1024 + t] = packdw(bx);
    } else {
        int cb = bx - 92;
        uint4* dst = (uint4*)wtail;
        dst[(d * NLC + cb) * 1024 + t] = make_uint4(packdw(92 + cb * 4), packdw(93 + cb * 4),
                                                    packdw(94 + cb * 4), packdw(95 + cb * 4));
    }
}

// ---------------- input projections: zxp[d][s][unit*4+gate] = (x_s @ w_ih^T + b) ----------------
__global__ __launch_bounds__(256) void k_zx(const int* __restrict__ sentence,
                                            const float* __restrict__ embed,
                                            const float* __restrict__ wT,
                                            const float* __restrict__ bf,
                                            const float* __restrict__ bb,
                                            float* __restrict__ zxp) {
    int d = blockIdx.y;
    int s0 = blockIdx.x * 16;
    const float* bias = d ? bb : bf;
    __shared__ float xbuf[16][EDIM];
    int u = threadIdx.x;   // unit 0..255
    for (int r = 0; r < 16; r++) {
        int row = sentence[s0 + r];
        xbuf[r][u] = embed[(long)row * EDIM + u];
    }
    __syncthreads();
    const float* wTd = wT + (long)d * EDIM * G4;
    float4 a[16];
    float4 bv = make_float4(bias[u], bias[256 + u], bias[512 + u], bias[768 + u]);
#pragma unroll
    for (int r = 0; r < 16; r++) a[r] = bv;
    for (int e = 0; e < EDIM; e += 4) {
        float w0[4], w1[4], w2[4], w3[4];
#pragma unroll
        for (int k = 0; k < 4; k++) {
            w0[k] = wTd[(long)(e + k) * G4 + u];
            w1[k] = wTd[(long)(e + k) * G4 + 256 + u];
            w2[k] = wTd[(long)(e + k) * G4 + 512 + u];
            w3[k] = wTd[(long)(e + k) * G4 + 768 + u];
        }
#pragma unroll
        for (int r = 0; r < 16; r++) {
            float4 x4 = *(const float4*)&xbuf[r][e];
            float xv[4] = {x4.x, x4.y, x4.z, x4.w};
#pragma unroll
            for (int k = 0; k < 4; k++) {
                a[r].x += w0[k] * xv[k];
                a[r].y += w1[k] * xv[k];
                a[r].z += w2[k] * xv[k];
                a[r].w += w3[k] * xv[k];
            }
        }
    }
#pragma unroll
    for (int r = 0; r < 16; r++)
        *(float4*)&zxp[(long)(d * SLEN + s0 + r) * G4 + u * 4] = a[r];
}

// ---------------- the serial BiLSTM: 2 blocks (one per direction) ----------------
// K-split-4: wave reads only 8 h b128/step; each lane accumulates all 4 gates of its
// unit, so after the xor16/xor32 butterfly there is no gate-gather phase at all.
__global__ __launch_bounds__(1024, 4) void k_lstm(const float* __restrict__ zxp,
                                                  const uint32_t* __restrict__ wpack,
                                                  const uint4* __restrict__ wtail,
                                                  const float* __restrict__ h0,
                                                  const float* __restrict__ c0,
                                                  float* __restrict__ hs) {
    extern __shared__ char smem[];
    char* hbase = smem;                     // [2][4 quarters][HPAD bytes]
    uint4* tail = (uint4*)(smem + 2048);    // [NLC][1024] per-thread tail weights

    int d = blockIdx.x;
    int t = threadIdx.x;
    int l = t & 63;
    int w = t >> 6;
    int kq = l >> 4;
    int lj = l & 15;
    int j = (w << 4) | lj;   // unit

    uint32_t wreg[92];
#pragma unroll
    for (int kk = 0; kk < 92; kk++) wreg[kk] = wpack[(d * 92 + kk) * 1024 + t];

    // stage tail weights into LDS (per-thread, lane-consecutive 16B -> conflict-free)
#pragma unroll
    for (int cb = 0; cb < NLC; cb++)
        tail[cb * 1024 + t] = wtail[(d * NLC + cb) * 1024 + t];

    float c = c0[d * HD + j];
    if (t < 128) {
        int u2 = 2 * t;
        half2_t p = {(half_t)h0[d * HD + u2], (half_t)h0[d * HD + u2 + 1]};
        *(uint32_t*)(hbase + (u2 >> 6) * HPAD + (u2 & 63) * 2) = __builtin_bit_cast(uint32_t, p);
    }
    __syncthreads();

    const float* zxd = zxp + (long)d * SLEN * G4;
    float* hsd = hs + (long)d * SLEN * HD + j;

    // software-pipelined zx read (hides LLC latency)
    int sx0 = d ? (SLEN - 1) : 0;
    float4 zxn = *(const float4*)&zxd[(long)sx0 * G4 + j * 4];

    for (int s = 0; s < SLEN; s++) {
        const int p = s & 1;
        float4 zx = zxn;
        if (s + 1 < SLEN) {
            int sxn = d ? (SLEN - 2 - s) : (s + 1);
            zxn = *(const float4*)&zxd[(long)sxn * G4 + j * 4];
        }

        const uint4* hq = (const uint4*)(hbase + p * HBUF + kq * HPAD);
        float aI0 = 0.f, aI1 = 0.f, aF0 = 0.f, aF1 = 0.f;
        float aG0 = 0.f, aG1 = 0.f, aO0 = 0.f, aO1 = 0.f;
#pragma unroll
        for (int cc = 0; cc < 8; cc++) {
            uint4 hv = hq[cc];
            aI0 = dot2(wreg[4 * cc + 0], hv.x, aI0);
            aI1 = dot2(wreg[4 * cc + 1], hv.y, aI1);
            aI0 = dot2(wreg[4 * cc + 2], hv.z, aI0);
            aI1 = dot2(wreg[4 * cc + 3], hv.w, aI1);
            aF0 = dot2(wreg[32 + 4 * cc + 0], hv.x, aF0);
            aF1 = dot2(wreg[32 + 4 * cc + 1], hv.y, aF1);
            aF0 = dot2(wreg[32 + 4 * cc + 2], hv.z, aF0);
            aF1 = dot2(wreg[32 + 4 * cc + 3], hv.w, aF1);
            if (cc < 7) {
                aG0 = dot2(wreg[64 + 4 * cc + 0], hv.x, aG0);
                aG1 = dot2(wreg[64 + 4 * cc + 1], hv.y, aG1);
                aG0 = dot2(wreg[64 + 4 * cc + 2], hv.z, aG0);
                aG1 = dot2(wreg[64 + 4 * cc + 3], hv.w, aG1);
            } else {
                uint4 tw = tail[t];   // chunk 23 = gate g, last K-chunk
                aG0 = dot2(tw.x, hv.x, aG0);
                aG1 = dot2(tw.y, hv.y, aG1);
                aG0 = dot2(tw.z, hv.z, aG0);
                aG1 = dot2(tw.w, hv.w, aG1);
            }
            uint4 ow = tail[(1 + cc) * 1024 + t];   // chunks 24..31 = gate o
            aO0 = dot2(ow.x, hv.x, aO0);
            aO1 = dot2(ow.y, hv.y, aO1);
            aO0 = dot2(ow.z, hv.z, aO0);
            aO1 = dot2(ow.w, hv.w, aO1);
        }

        float zi = aI0 + aI1, zf = aF0 + aF1, zg = aG0 + aG1, zo = aO0 + aO1;
        // butterfly over the 4 K-quarters: xor16 then xor32
        zi += __shfl_xor(zi, 16, 64);
        zf += __shfl_xor(zf, 16, 64);
        zg += __shfl_xor(zg, 16, 64);
        zo += __shfl_xor(zo, 16, 64);
        zi += __shfl_xor(zi, 32, 64);
        zf += __shfl_xor(zf, 32, 64);
        zg += __shfl_xor(zg, 32, 64);
        zo += __shfl_xor(zo, 32, 64);
        zi += zx.x; zf += zx.y; zg += zx.z; zo += zx.w;

        float ig = fsig(zi), fg = fsig(zf), og = fsig(zo);
        float gg = ftanh(zg);
        c = fg * c + ig * gg;
        float hval = og * ftanh(c);
        if (l < 16) {
            int sx = d ? (SLEN - 1 - s) : s;
            hsd[(long)sx * HD] = hval;
            *(half_t*)(hbase + (p ^ 1) * HBUF + (j >> 6) * HPAD + (j & 63) * 2) = (half_t)hval;
        }
        __syncthreads();
    }
}

// ---------------- feats[s][k] = emitW[k] . [h_fwd[s], h_bwd[s]] + emit_b[k] ----------------
__global__ __launch_bounds__(192) void k_feats(const float* __restrict__ hs,
                                               const float* __restrict__ emitW,
                                               const float* __restrict__ emitb,
                                               float* __restrict__ feats) {
    __shared__ float wb[KT][516];
    __shared__ float hb[8][516];
    int tid = threadIdx.x;
    int s0 = blockIdx.x * 8;
    for (int idx = tid; idx < KT * 512; idx += 192) {
        wb[idx >> 9][idx & 511] = emitW[idx];
    }
    for (int idx = tid; idx < 8 * 512; idx += 192) {
        int sl = idx >> 9, jj = idx & 511;
        float v = (jj < 256) ? hs[(long)(s0 + sl) * HD + jj]
                             : hs[(long)(SLEN + s0 + sl) * HD + (jj - 256)];
        hb[sl][jj] = v;
    }
    __syncthreads();
    if (tid < 160) {
        int sl = tid / KT, k = tid % KT;
        float acc = emitb[k];
        for (int jj = 0; jj < 512; jj += 4) {
            float4 wv = *(const float4*)&wb[k][jj];
            float4 hv = *(const float4*)&hb[sl][jj];
            acc += wv.x * hv.x + wv.y * hv.y + wv.z * hv.z + wv.w * hv.w;
        }
        feats[(long)(s0 + sl) * KT + k] = acc;
    }
}

// ---------------- gold path score -> out[1] ----------------
__global__ __launch_bounds__(256) void k_gold(const float* __restrict__ feats,
                                              const int* __restrict__ tags,
                                              const float* __restrict__ trans,
                                              float* __restrict__ out) {
    __shared__ float red[256];
    int tid = threadIdx.x;
    float local = 0.f;
    for (int s2 = tid; s2 < SLEN; s2 += 256) {
        int cur = tags[s2];
        int prev = s2 ? tags[s2 - 1] : START_ID;
        local += trans[cur * KT + prev] + feats[(long)s2 * KT + cur];
    }
    red[tid] = local;
    __syncthreads();
    for (int off = 128; off; off >>= 1) {
        if (tid < off) red[tid] += red[tid + off];
        __syncthreads();
    }
    if (tid == 0) out[1] = red[0] + trans[STOP_ID * KT + tags[SLEN - 1]];
}

// ---------------- CRF: chunk of 16 step-matrices -> one 20x20 log-space matrix ----------------
__global__ __launch_bounds__(512) void k_crf_chunk(const float* __restrict__ feats,
                                                   const float* __restrict__ trans,
                                                   float* __restrict__ mats) {
    __shared__ float T[KT][KT + 1];
    __shared__ float fb[16][KT];
    __shared__ float cur[2][KT][KT + 1];
    int tid = threadIdx.x;
    int t0 = blockIdx.x * 16;
    if (tid < KT * KT) T[tid / KT][tid % KT] = trans[tid];
    for (int idx = tid; idx < 16 * KT; idx += 512) fb[idx / KT][idx % KT] = feats[(long)t0 * KT + idx];
    __syncthreads();
    int i = tid / KT, jc = tid % KT;
    bool act = tid < KT * KT;
    if (act) cur[0][i][jc] = T[i][jc] + fb[0][i];
    __syncthreads();
    for (int m = 1; m < 16; m++) {
        int p = (m - 1) & 1;
        float nv = 0.f;
        if (act) {
            float vs[KT], vmax = -1e30f;
#pragma unroll
            for (int k = 0; k < KT; k++) { vs[k] = T[i][k] + cur[p][k][jc]; vmax = fmaxf(vmax, vs[k]); }
            float sum = 0.f;
#pragma unroll
            for (int k = 0; k < KT; k++) sum += __expf(vs[k] - vmax);
            nv = fb[m][i] + vmax + __logf(sum);
        }
        if (act) cur[p ^ 1][i][jc] = nv;
        __syncthreads();
    }
    if (act) mats[(long)blockIdx.x * (KT * KT) + tid] = cur[1][i][jc];
}

// ---------------- CRF: combine per_block consecutive matrices (left-applied) ----------------
__global__ __launch_bounds__(512) void k_crf_combine(const float* __restrict__ in,
                                                     float* __restrict__ out_mats,
                                                     int per_block,
                                                     const float* __restrict__ trans,
                                                     float* __restrict__ d_out_ptr,
                                                     int finalize) {
    __shared__ float A[KT][KT + 1];
    __shared__ float cur[2][KT][KT + 1];
    int tid = threadIdx.x;
    int b = blockIdx.x;
    int i = tid / KT, jc = tid % KT;
    bool act = tid < KT * KT;
    const float* base = in + (long)b * per_block * (KT * KT);
    if (act) cur[0][i][jc] = base[tid];
    __syncthreads();
    for (int m = 1; m < per_block; m++) {
        int p = (m - 1) & 1;
        if (act) A[i][jc] = base[(long)m * KT * KT + tid];
        __syncthreads();
        float nv = 0.f;
        if (act) {
            float vs[KT], vmax = -1e30f;
#pragma unroll
            for (int k = 0; k < KT; k++) { vs[k] = A[i][k] + cur[p][k][jc]; vmax = fmaxf(vmax, vs[k]); }
            float sum = 0.f;
#pragma unroll
            for (int k = 0; k < KT; k++) sum += __expf(vs[k] - vmax);
            nv = vmax + __logf(sum);
        }
        if (act) cur[p ^ 1][i][jc] = nv;
        __syncthreads();
    }
    int fbuf = (per_block - 1) & 1;
    if (!finalize) {
        if (act) out_mats[(long)b * KT * KT + tid] = cur[fbuf][i][jc];
        return;
    }
    if (tid == 0) {
        float fv[KT];
        for (int ii = 0; ii < KT; ii++) {
            float vs[KT], vmax = -1e30f;
            for (int k = 0; k < KT; k++) {
                float v = cur[fbuf][ii][k] + (k == START_ID ? 0.f : -10000.f);
                vs[k] = v;
                vmax = fmaxf(vmax, v);
            }
            float sum = 0.f;
            for (int k = 0; k < KT; k++) sum += __expf(vs[k] - vmax);
            fv[ii] = vmax + __logf(sum);
        }
        float vs2[KT], vmax = -1e30f;
        for (int ii = 0; ii < KT; ii++) {
            float v = fv[ii] + trans[STOP_ID * KT + ii];
            vs2[ii] = v;
            vmax = fmaxf(vmax, v);
        }
        float sum = 0.f;
        for (int ii = 0; ii < KT; ii++) sum += __expf(vs2[ii] - vmax);
        d_out_ptr[0] = vmax + __logf(sum);
    }
}

extern "C" void kernel_launch(void* const* d_in, const int* in_sizes, int n_in,
                              void* d_out, int out_size, void* d_ws, size_t ws_size,
                              hipStream_t stream) {
    const int* sentence = (const int*)d_in[0];
    const int* tags = (const int*)d_in[1];
    const float* embed = (const float*)d_in[2];
    const float* w_ih_f = (const float*)d_in[3];
    const float* w_hh_f = (const float*)d_in[4];
    const float* b_f = (const float*)d_in[5];
    const float* w_ih_b = (const float*)d_in[6];
    const float* w_hh_b = (const float*)d_in[7];
    const float* b_b = (const float*)d_in[8];
    const float* h0 = (const float*)d_in[9];
    const float* c0 = (const float*)d_in[10];
    const float* emit_W = (const float*)d_in[11];
    const float* emit_b = (const float*)d_in[12];
    const float* transition = (const float*)d_in[13];
    float* out = (float*)d_out;

    char* ws = (char*)d_ws;
    float* zxp = (float*)(ws + 0);                       // 2*4096*1024 f32 = 32 MB
    float* hs = (float*)(ws + 33554432);                 // 2*4096*256 f32  = 8 MB
    float* wT = (float*)(ws + 41943040);                 // 2*256*1024 f32  = 2 MB
    uint32_t* wpack = (uint32_t*)(ws + 44040192);        // 2*92*1024 u32 = 736 KB
    uint32_t* wtail = (uint32_t*)(ws + 44793856);        // 2*9*1024*4 u32 = 288 KB
    float* feats = (float*)(ws + 45088768);              // 4096*20 f32
    float* mats = (float*)(ws + 45416448);               // 256*400 f32
    float* mats2 = (float*)(ws + 45826048);              // 16*400 f32

    // opt-in to >64KB dynamic LDS for k_lstm (idempotent host call, not a stream op)
    (void)hipFuncSetAttribute((const void*)k_lstm,
                              hipFuncAttributeMaxDynamicSharedMemorySize,
                              LSTM_LDS_BYTES);

    k_transpose_ih<<<dim3(32, 8, 2), 256, 0, stream>>>(w_ih_f, w_ih_b, wT);
    k_pack_hh<<<dim3(101, 2), 1024, 0, stream>>>(w_hh_f, w_hh_b, wpack, wtail);
    k_zx<<<dim3(256, 2), 256, 0, stream>>>(sentence, embed, wT, b_f, b_b, zxp);
    k_lstm<<<dim3(2), 1024, LSTM_LDS_BYTES, stream>>>(zxp, wpack, (const uint4*)wtail, h0, c0, hs);
    k_feats<<<dim3(512), 192, 0, stream>>>(hs, emit_W, emit_b, feats);
    k_gold<<<dim3(1), 256, 0, stream>>>(feats, tags, transition, out);
    k_crf_chunk<<<dim3(256), 512, 0, stream>>>(feats, transition, mats);
    k_crf_combine<<<dim3(16), 512, 0, stream>>>(mats, mats2, 16, transition, out, 0);
    k_crf_combine<<<dim3(1), 512, 0, stream>>>(mats2, nullptr, 16, transition, out, 1);
}

// Round 5
// 9001.017 us; speedup vs baseline: 1.0104x; 1.0104x over previous
//
#include <hip/hip_runtime.h>
#include <stdint.h>

#define SLEN 4096
#define EDIM 256
#define HD 256
#define G4 1024   // 4*HD
#define KT 20
#define START_ID 18
#define STOP_ID 19

typedef _Float16 half_t;
typedef _Float16 half2_t __attribute__((ext_vector_type(2)));

__device__ __forceinline__ float dot2(uint32_t w, uint32_t h, float acc) {
#if __has_builtin(__builtin_amdgcn_fdot2)
    return __builtin_amdgcn_fdot2(__builtin_bit_cast(half2_t, w),
                                  __builtin_bit_cast(half2_t, h), acc, false);
#else
    half2_t wv = __builtin_bit_cast(half2_t, w);
    half2_t hv = __builtin_bit_cast(half2_t, h);
    acc += (float)wv.x * (float)hv.x;
    acc += (float)wv.y * (float)hv.y;
    return acc;
#endif
}

__device__ __forceinline__ float fsig(float x) { return 1.f / (1.f + __expf(-x)); }
__device__ __forceinline__ float ftanh(float x) { return 1.f - 2.f / (__expf(2.f * x) + 1.f); }

// ===== k_lstm 4-block decomposition =====
// block b = d*2 + half. Block owns units [half*128, half*128+128) of direction d.
// thread t: w=t>>6, l=t&63; ju = (w&7)*16 + (l&15) (unit-local 0..127), j = half*128+ju.
// kqg = w>>3; kq = kqg*4 + (l>>4): K-slice [kq*32, kq*32+32).
// Own-slice waves (kqg==half) read h from local LDS; partner-slice waves (kqg!=half)
// poll the partner block's flag and read its published h-half from global (LLC).
// Per thread: 4 gates x 32 halfs = 16 uint4 weights, all in VGPRs.
// Reduce: xor16+xor32 butterfly sums the wave's 4 K-slices; cross-wave-group partial
// (zpart, LDS) adds the other 4; own-slice waves finish activations and write h.

// ---------------- prep: transpose w_ih into [d][e][o] ----------------
__global__ __launch_bounds__(256) void k_transpose_ih(const float* __restrict__ wf,
                                                      const float* __restrict__ wb,
                                                      float* __restrict__ wT) {
    __shared__ float tile[32][33];
    int d = blockIdx.z;
    const float* w = d ? wb : wf;
    int ob = blockIdx.x * 32;  // over 1024 rows
    int eb = blockIdx.y * 32;  // over 256 cols
    int tx = threadIdx.x & 31, ty = threadIdx.x >> 5;
#pragma unroll
    for (int r = 0; r < 32; r += 8)
        tile[ty + r][tx] = w[(long)(ob + ty + r) * EDIM + eb + tx];
    __syncthreads();
    float* dst = wT + (long)d * EDIM * G4;
#pragma unroll
    for (int r = 0; r < 32; r += 8)
        dst[(long)(eb + ty + r) * G4 + ob + tx] = tile[tx][ty + r];
}

// ---------------- prep: pack w_hh to fp16 in 4-block lstm thread order; zero flags ----------------
__global__ __launch_bounds__(1024) void k_pack_hh(const float* __restrict__ whf,
                                                  const float* __restrict__ whb,
                                                  uint4* __restrict__ wpack,
                                                  uint32_t* __restrict__ flags) {
    int b = blockIdx.x;            // 0..3 = d*2 + half
    int d = b >> 1, half = b & 1;
    const float* W = d ? whb : whf;
    int t = threadIdx.x;
    int l = t & 63, w = t >> 6;
    int ju = ((w & 7) << 4) | (l & 15);
    int kq = ((w >> 3) << 2) | (l >> 4);
    if (b == 0 && t < 4) flags[t] = 0;   // per-launch flag reset (graph-replay safe)
#pragma unroll
    for (int cc = 0; cc < 16; cc++) {
        int g = cc >> 2, kc = cc & 3;
        int row = g * 256 + half * 128 + ju;
        int kb = kq * 32 + kc * 8;
        uint32_t q[4];
#pragma unroll
        for (int dw = 0; dw < 4; dw++) {
            half2_t p = {(half_t)W[(long)row * HD + kb + 2 * dw],
                         (half_t)W[(long)row * HD + kb + 2 * dw + 1]};
            q[dw] = __builtin_bit_cast(uint32_t, p);
        }
        wpack[(b * 16 + cc) * 1024 + t] = make_uint4(q[0], q[1], q[2], q[3]);
    }
}

// ---------------- input projections: zxp[d][s][unit*4+gate] = (x_s @ w_ih^T + b) ----------------
__global__ __launch_bounds__(256) void k_zx(const int* __restrict__ sentence,
                                            const float* __restrict__ embed,
                                            const float* __restrict__ wT,
                                            const float* __restrict__ bf,
                                            const float* __restrict__ bb,
                                            float* __restrict__ zxp) {
    int d = blockIdx.y;
    int s0 = blockIdx.x * 16;
    const float* bias = d ? bb : bf;
    __shared__ float xbuf[16][EDIM];
    int u = threadIdx.x;   // unit 0..255
    for (int r = 0; r < 16; r++) {
        int row = sentence[s0 + r];
        xbuf[r][u] = embed[(long)row * EDIM + u];
    }
    __syncthreads();
    const float* wTd = wT + (long)d * EDIM * G4;
    float4 a[16];
    float4 bv = make_float4(bias[u], bias[256 + u], bias[512 + u], bias[768 + u]);
#pragma unroll
    for (int r = 0; r < 16; r++) a[r] = bv;
    for (int e = 0; e < EDIM; e += 4) {
        float w0[4], w1[4], w2[4], w3[4];
#pragma unroll
        for (int k = 0; k < 4; k++) {
            w0[k] = wTd[(long)(e + k) * G4 + u];
            w1[k] = wTd[(long)(e + k) * G4 + 256 + u];
            w2[k] = wTd[(long)(e + k) * G4 + 512 + u];
            w3[k] = wTd[(long)(e + k) * G4 + 768 + u];
        }
#pragma unroll
        for (int r = 0; r < 16; r++) {
            float4 x4 = *(const float4*)&xbuf[r][e];
            float xv[4] = {x4.x, x4.y, x4.z, x4.w};
#pragma unroll
            for (int k = 0; k < 4; k++) {
                a[r].x += w0[k] * xv[k];
                a[r].y += w1[k] * xv[k];
                a[r].z += w2[k] * xv[k];
                a[r].w += w3[k] * xv[k];
            }
        }
    }
#pragma unroll
    for (int r = 0; r < 16; r++)
        *(float4*)&zxp[(long)(d * SLEN + s0 + r) * G4 + u * 4] = a[r];
}

// ---------------- the serial BiLSTM: 4 blocks (direction x unit-half) ----------------
__global__ __launch_bounds__(1024, 4) void k_lstm(const float* __restrict__ zxp,
                                                  const uint4* __restrict__ wpack,
                                                  const float* __restrict__ h0,
                                                  const float* __restrict__ c0,
                                                  float* __restrict__ hs,
                                                  uint32_t* __restrict__ hx,
                                                  uint32_t* __restrict__ flags) {
    __shared__ __align__(16) half_t hfull[256];     // step-0 h (both halves)
    __shared__ __align__(16) half_t hown[2][128];   // own-half h double buffer
    __shared__ __align__(16) float zpart[128][4];   // cross-wave-group partials

    int b = blockIdx.x, d = b >> 1, half = b & 1;
    int t = threadIdx.x, l = t & 63, w = t >> 6;
    int kqg = w >> 3;
    bool ownw = (kqg == half);           // this wave's K-slices cover OWN units
    int ju = ((w & 7) << 4) | (l & 15);  // unit-local 0..127
    int j = (half << 7) | ju;            // global unit
    int kq = (kqg << 2) | (l >> 4);      // K-slice index 0..7

    const uint4* wpd = wpack + (long)(b << 4) * 1024;
    uint4 wreg[16];
#pragma unroll
    for (int cc = 0; cc < 16; cc++) wreg[cc] = wpd[cc * 1024 + t];

    float c = c0[d * HD + j];
    if (t < 128) {
        half2_t p0 = {(half_t)h0[d * HD + 2 * t], (half_t)h0[d * HD + 2 * t + 1]};
        ((uint32_t*)hfull)[t] = __builtin_bit_cast(uint32_t, p0);
    }
    __syncthreads();

    const float* zxd = zxp + (long)d * SLEN * G4;
    float* hsd = hs + (long)d * SLEN * HD + j;
    uint32_t* hx_mine = hx + b * 128;            // [b][parity][64] u32
    const uint32_t* hx_part = hx + (b ^ 1) * 128;
    uint32_t* mflag = flags + b;
    uint32_t* pflag = flags + (b ^ 1);
    const int pubw = half ? 7 : 15;              // a partner-slice wave (idle in phase B)

    float4 zxn = make_float4(0.f, 0.f, 0.f, 0.f);
    if (ownw) zxn = *(const float4*)&zxd[(long)(d ? SLEN - 1 : 0) * G4 + j * 4];

    for (int s = 0; s < SLEN; s++) {
        const int p = s & 1;
        float4 zxq = zxn;
        if (ownw && s + 1 < SLEN) {
            int sxn = d ? (SLEN - 2 - s) : (s + 1);
            zxn = *(const float4*)&zxd[(long)sxn * G4 + j * 4];
        }

        uint4 hv0, hv1, hv2, hv3;
        if (s == 0) {
            const char* hb = (const char*)hfull + (kq << 6);
            hv0 = *(const uint4*)(hb);      hv1 = *(const uint4*)(hb + 16);
            hv2 = *(const uint4*)(hb + 32); hv3 = *(const uint4*)(hb + 48);
        } else if (ownw) {
            const char* hb = (const char*)hown + p * 256 + ((l >> 4) << 6);
            hv0 = *(const uint4*)(hb);      hv1 = *(const uint4*)(hb + 16);
            hv2 = *(const uint4*)(hb + 32); hv3 = *(const uint4*)(hb + 48);
        } else {
            // wait for partner's h_s, then read it from LLC (sc1 loads bypass stale L2)
            const uint32_t tgt = (uint32_t)s;
            while (__hip_atomic_load(pflag, __ATOMIC_RELAXED, __HIP_MEMORY_SCOPE_AGENT) < tgt)
                __builtin_amdgcn_s_sleep(2);
            asm volatile("" ::: "memory");
            const uint32_t* src = hx_part + p * 64 + ((l >> 4) << 4);
            uint32_t hw[16];
#pragma unroll
            for (int q2 = 0; q2 < 16; q2++)
                hw[q2] = __hip_atomic_load(src + q2, __ATOMIC_RELAXED, __HIP_MEMORY_SCOPE_AGENT);
            hv0 = make_uint4(hw[0], hw[1], hw[2], hw[3]);
            hv1 = make_uint4(hw[4], hw[5], hw[6], hw[7]);
            hv2 = make_uint4(hw[8], hw[9], hw[10], hw[11]);
            hv3 = make_uint4(hw[12], hw[13], hw[14], hw[15]);
        }

        float a0 = 0.f, b0 = 0.f, a1 = 0.f, b1 = 0.f;
        float a2 = 0.f, b2 = 0.f, a3 = 0.f, b3 = 0.f;
#define DOT4(kc, HV)                                                      \
        a0 = dot2(wreg[kc].x, HV.x, a0);      b0 = dot2(wreg[kc].y, HV.y, b0);      \
        a0 = dot2(wreg[kc].z, HV.z, a0);      b0 = dot2(wreg[kc].w, HV.w, b0);      \
        a1 = dot2(wreg[4 + kc].x, HV.x, a1);  b1 = dot2(wreg[4 + kc].y, HV.y, b1);  \
        a1 = dot2(wreg[4 + kc].z, HV.z, a1);  b1 = dot2(wreg[4 + kc].w, HV.w, b1);  \
        a2 = dot2(wreg[8 + kc].x, HV.x, a2);  b2 = dot2(wreg[8 + kc].y, HV.y, b2);  \
        a2 = dot2(wreg[8 + kc].z, HV.z, a2);  b2 = dot2(wreg[8 + kc].w, HV.w, b2);  \
        a3 = dot2(wreg[12 + kc].x, HV.x, a3); b3 = dot2(wreg[12 + kc].y, HV.y, b3); \
        a3 = dot2(wreg[12 + kc].z, HV.z, a3); b3 = dot2(wreg[12 + kc].w, HV.w, b3);
        DOT4(0, hv0)
        DOT4(1, hv1)
        DOT4(2, hv2)
        DOT4(3, hv3)
#undef DOT4
        float zi = a0 + b0, zf = a1 + b1, zg = a2 + b2, zo = a3 + b3;
        // butterfly over this wave's 4 K-slices
        zi += __shfl_xor(zi, 16, 64);
        zf += __shfl_xor(zf, 16, 64);
        zg += __shfl_xor(zg, 16, 64);
        zo += __shfl_xor(zo, 16, 64);
        zi += __shfl_xor(zi, 32, 64);
        zf += __shfl_xor(zf, 32, 64);
        zg += __shfl_xor(zg, 32, 64);
        zo += __shfl_xor(zo, 32, 64);

        if (!ownw && (l >> 4) == 0)
            *(float4*)&zpart[ju][0] = make_float4(zi, zf, zg, zo);
        __syncthreads();   // B1: partner-slice partials published

        if (ownw) {
            float4 zp = *(const float4*)&zpart[ju][0];
            float Zi = zi + zp.x + zxq.x;
            float Zf = zf + zp.y + zxq.y;
            float Zg = zg + zp.z + zxq.z;
            float Zo = zo + zp.w + zxq.w;
            float ig = fsig(Zi), fg = fsig(Zf), og = fsig(Zo);
            float gg = ftanh(Zg);
            c = fg * c + ig * gg;
            float hval = og * ftanh(c);
            if ((l >> 4) == 0) {
                int sx = d ? (SLEN - 1 - s) : s;
                hsd[(long)sx * HD] = hval;
                hown[p ^ 1][ju] = (half_t)hval;
            }
        }
        __syncthreads();   // B2: new own-half h visible in LDS

        // publish h_{s+1} to partner (one otherwise-idle wave)
        if (w == pubw && s + 1 < SLEN) {
            if (l < 16) {
                uint4 v = *(const uint4*)((const char*)hown + (p ^ 1) * 256 + l * 16);
                *(uint4*)(hx_mine + (p ^ 1) * 64 + l * 4) = v;
            }
            __threadfence();   // drain stores + L2 writeback to LLC
            if (l == 0)
                __hip_atomic_store(mflag, (uint32_t)(s + 1), __ATOMIC_RELEASE,
                                   __HIP_MEMORY_SCOPE_AGENT);
        }
    }
}

// ---------------- feats[s][k] = emitW[k] . [h_fwd[s], h_bwd[s]] + emit_b[k] ----------------
__global__ __launch_bounds__(192) void k_feats(const float* __restrict__ hs,
                                               const float* __restrict__ emitW,
                                               const float* __restrict__ emitb,
                                               float* __restrict__ feats) {
    __shared__ float wb[KT][516];
    __shared__ float hb[8][516];
    int tid = threadIdx.x;
    int s0 = blockIdx.x * 8;
    for (int idx = tid; idx < KT * 512; idx += 192) {
        wb[idx >> 9][idx & 511] = emitW[idx];
    }
    for (int idx = tid; idx < 8 * 512; idx += 192) {
        int sl = idx >> 9, jj = idx & 511;
        float v = (jj < 256) ? hs[(long)(s0 + sl) * HD + jj]
                             : hs[(long)(SLEN + s0 + sl) * HD + (jj - 256)];
        hb[sl][jj] = v;
    }
    __syncthreads();
    if (tid < 160) {
        int sl = tid / KT, k = tid % KT;
        float acc = emitb[k];
        for (int jj = 0; jj < 512; jj += 4) {
            float4 wv = *(const float4*)&wb[k][jj];
            float4 hv = *(const float4*)&hb[sl][jj];
            acc += wv.x * hv.x + wv.y * hv.y + wv.z * hv.z + wv.w * hv.w;
        }
        feats[(long)(s0 + sl) * KT + k] = acc;
    }
}

// ---------------- gold path score -> out[1] ----------------
__global__ __launch_bounds__(256) void k_gold(const float* __restrict__ feats,
                                              const int* __restrict__ tags,
                                              const float* __restrict__ trans,
                                              float* __restrict__ out) {
    __shared__ float red[256];
    int tid = threadIdx.x;
    float local = 0.f;
    for (int s2 = tid; s2 < SLEN; s2 += 256) {
        int cur = tags[s2];
        int prev = s2 ? tags[s2 - 1] : START_ID;
        local += trans[cur * KT + prev] + feats[(long)s2 * KT + cur];
    }
    red[tid] = local;
    __syncthreads();
    for (int off = 128; off; off >>= 1) {
        if (tid < off) red[tid] += red[tid + off];
        __syncthreads();
    }
    if (tid == 0) out[1] = red[0] + trans[STOP_ID * KT + tags[SLEN - 1]];
}

// ---------------- CRF: chunk of 16 step-matrices -> one 20x20 log-space matrix ----------------
__global__ __launch_bounds__(512) void k_crf_chunk(const float* __restrict__ feats,
                                                   const float* __restrict__ trans,
                                                   float* __restrict__ mats) {
    __shared__ float T[KT][KT + 1];
    __shared__ float fb[16][KT];
    __shared__ float cur[2][KT][KT + 1];
    int tid = threadIdx.x;
    int t0 = blockIdx.x * 16;
    if (tid < KT * KT) T[tid / KT][tid % KT] = trans[tid];
    for (int idx = tid; idx < 16 * KT; idx += 512) fb[idx / KT][idx % KT] = feats[(long)t0 * KT + idx];
    __syncthreads();
    int i = tid / KT, jc = tid % KT;
    bool act = tid < KT * KT;
    if (act) cur[0][i][jc] = T[i][jc] + fb[0][i];
    __syncthreads();
    for (int m = 1; m < 16; m++) {
        int p = (m - 1) & 1;
        float nv = 0.f;
        if (act) {
            float vs[KT], vmax = -1e30f;
#pragma unroll
            for (int k = 0; k < KT; k++) { vs[k] = T[i][k] + cur[p][k][jc]; vmax = fmaxf(vmax, vs[k]); }
            float sum = 0.f;
#pragma unroll
            for (int k = 0; k < KT; k++) sum += __expf(vs[k] - vmax);
            nv = fb[m][i] + vmax + __logf(sum);
        }
        if (act) cur[p ^ 1][i][jc] = nv;
        __syncthreads();
    }
    if (act) mats[(long)blockIdx.x * (KT * KT) + tid] = cur[1][i][jc];
}

// ---------------- CRF: combine per_block consecutive matrices (left-applied) ----------------
__global__ __launch_bounds__(512) void k_crf_combine(const float* __restrict__ in,
                                                     float* __restrict__ out_mats,
                                                     int per_block,
                                                     const float* __restrict__ trans,
                                                     float* __restrict__ d_out_ptr,
                                                     int finalize) {
    __shared__ float A[KT][KT + 1];
    __shared__ float cur[2][KT][KT + 1];
    int tid = threadIdx.x;
    int b = blockIdx.x;
    int i = tid / KT, jc = tid % KT;
    bool act = tid < KT * KT;
    const float* base = in + (long)b * per_block * (KT * KT);
    if (act) cur[0][i][jc] = base[tid];
    __syncthreads();
    for (int m = 1; m < per_block; m++) {
        int p = (m - 1) & 1;
        if (act) A[i][jc] = base[(long)m * KT * KT + tid];
        __syncthreads();
        float nv = 0.f;
        if (act) {
            float vs[KT], vmax = -1e30f;
#pragma unroll
            for (int k = 0; k < KT; k++) { vs[k] = A[i][k] + cur[p][k][jc]; vmax = fmaxf(vmax, vs[k]); }
            float sum = 0.f;
#pragma unroll
            for (int k = 0; k < KT; k++) sum += __expf(vs[k] - vmax);
            nv = vmax + __logf(sum);
        }
        if (act) cur[p ^ 1][i][jc] = nv;
        __syncthreads();
    }
    int fbuf = (per_block - 1) & 1;
    if (!finalize) {
        if (act) out_mats[(long)b * KT * KT + tid] = cur[fbuf][i][jc];
        return;
    }
    if (tid == 0) {
        float fv[KT];
        for (int ii = 0; ii < KT; ii++) {
            float vs[KT], vmax = -1e30f;
            for (int k = 0; k < KT; k++) {
                float v = cur[fbuf][ii][k] + (k == START_ID ? 0.f : -10000.f);
                vs[k] = v;
                vmax = fmaxf(vmax, v);
            }
            float sum = 0.f;
            for (int k = 0; k < KT; k++) sum += __expf(vs[k] - vmax);
            fv[ii] = vmax + __logf(sum);
        }
        float vs2[KT], vmax = -1e30f;
        for (int ii = 0; ii < KT; ii++) {
            float v = fv[ii] + trans[STOP_ID * KT + ii];
            vs2[ii] = v;
            vmax = fmaxf(vmax, v);
        }
        float sum = 0.f;
        for (int ii = 0; ii < KT; ii++) sum += __expf(vs2[ii] - vmax);
        d_out_ptr[0] = vmax + __logf(sum);
    }
}

extern "C" void kernel_launch(void* const* d_in, const int* in_sizes, int n_in,
                              void* d_out, int out_size, void* d_ws, size_t ws_size,
                              hipStream_t stream) {
    const int* sentence = (const int*)d_in[0];
    const int* tags = (const int*)d_in[1];
    const float* embed = (const float*)d_in[2];
    const float* w_ih_f = (const float*)d_in[3];
    const float* w_hh_f = (const float*)d_in[4];
    const float* b_f = (const float*)d_in[5];
    const float* w_ih_b = (const float*)d_in[6];
    const float* w_hh_b = (const float*)d_in[7];
    const float* b_b = (const float*)d_in[8];
    const float* h0 = (const float*)d_in[9];
    const float* c0 = (const float*)d_in[10];
    const float* emit_W = (const float*)d_in[11];
    const float* emit_b = (const float*)d_in[12];
    const float* transition = (const float*)d_in[13];
    float* out = (float*)d_out;

    char* ws = (char*)d_ws;
    float* zxp = (float*)(ws + 0);                       // 2*4096*1024 f32 = 32 MB
    float* hs = (float*)(ws + 33554432);                 // 2*4096*256 f32  = 8 MB
    float* wT = (float*)(ws + 41943040);                 // 2*256*1024 f32  = 2 MB
    uint4* wpack = (uint4*)(ws + 44040192);              // 4*16*1024 uint4 = 1 MB
    float* feats = (float*)(ws + 45088768);              // 4096*20 f32
    float* mats = (float*)(ws + 45416448);               // 256*400 f32
    float* mats2 = (float*)(ws + 45826048);              // 16*400 f32
    uint32_t* hx = (uint32_t*)(ws + 45851648);           // 4 blocks * 2 parity * 64 u32 = 2 KB
    uint32_t* flags = (uint32_t*)(ws + 45855744);        // 4 u32

    k_transpose_ih<<<dim3(32, 8, 2), 256, 0, stream>>>(w_ih_f, w_ih_b, wT);
    k_pack_hh<<<dim3(4), 1024, 0, stream>>>(w_hh_f, w_hh_b, wpack, flags);
    k_zx<<<dim3(256, 2), 256, 0, stream>>>(sentence, embed, wT, b_f, b_b, zxp);
    k_lstm<<<dim3(4), 1024, 0, stream>>>(zxp, wpack, h0, c0, hs, hx, flags);
    k_feats<<<dim3(512), 192, 0, stream>>>(hs, emit_W, emit_b, feats);
    k_gold<<<dim3(1), 256, 0, stream>>>(feats, tags, transition, out);
    k_crf_chunk<<<dim3(256), 512, 0, stream>>>(feats, transition, mats);
    k_crf_combine<<<dim3(16), 512, 0, stream>>>(mats, mats2, 16, transition, out, 0);
    k_crf_combine<<<dim3(1), 512, 0, stream>>>(mats2, nullptr, 16, transition, out, 1);
}